// Round 6
// baseline (185.058 us; speedup 1.0000x reference)
//
#include <hip/hip_runtime.h>
#include <cstdint>

typedef __attribute__((ext_vector_type(8))) short short8;      // 8 bf16 = 4 VGPRs
typedef __attribute__((ext_vector_type(4))) float floatx4;     // 16x16 MFMA C/D frag
typedef __attribute__((ext_vector_type(16))) float floatx16;   // 32x32 MFMA C/D frag
typedef __attribute__((ext_vector_type(4))) _Float16 half4;    // 16x16x16 f16 A/B frag
typedef __attribute__((ext_vector_type(8))) _Float16 half8;    // 32x32x16 f16 A/B frag

#define DEV __device__ __forceinline__

constexpr int NB = 2, Lseq = 2048, NH = 16, HD = 64, EMB = 1024;
// fold softmax scale (1/sqrt(1024)) and log2(e) into Wq so flash uses exp2
constexpr float QSCALE = 0.03125f * 1.4426950408889634f;

// pack two f32 -> two bf16 in one dword (round-half-up via bias, then v_perm)
DEV uint32_t pack2(float lo, float hi) {
  uint32_t a = __builtin_bit_cast(uint32_t, lo) + 0x8000u;
  uint32_t b = __builtin_bit_cast(uint32_t, hi) + 0x8000u;
  return __builtin_amdgcn_perm(b, a, 0x07060302);
}

DEV uint32_t packh2(float lo, float hi) {  // two f32 -> packed f16 dword
  return __builtin_bit_cast(uint32_t, __builtin_amdgcn_cvt_pkrtz(lo, hi));
}

DEV void gl_lds16(const void* g, void* l) {  // async global->LDS, 16B/lane
  __builtin_amdgcn_global_load_lds((const __attribute__((address_space(1))) void*)g,
                                   (__attribute__((address_space(3))) void*)l, 16, 0, 0);
}

// half-wave exchange: after call, x = [x_lo, y_lo], y = [x_hi, y_hi] (lane blocks of 32)
DEV void pl32(uint32_t& x, uint32_t& y) {
  typedef __attribute__((ext_vector_type(2))) unsigned int uint2v;
  uint2v r = __builtin_amdgcn_permlane32_swap(x, y, false, false);
  x = r[0];
  y = r[1];
}

// load 8 consecutive f32, scale, convert to a bf16 MFMA frag chunk
DEV short8 ld8bf(const float* p, float sc) {
  float4 u = *(const float4*)p;
  float4 v = *(const float4*)(p + 4);
  union { short8 s; uint32_t d[4]; } r;
  r.d[0] = pack2(u.x * sc, u.y * sc);
  r.d[1] = pack2(u.z * sc, u.w * sc);
  r.d[2] = pack2(v.x * sc, v.y * sc);
  r.d[3] = pack2(v.z * sc, v.w * sc);
  return r.s;
}

// ---------------- prep: Q/K/V projections (MFMA, LDS-free) + Wout cvt ----------------
__global__ __launch_bounds__(256) void prep_kernel(
    const float* __restrict__ values, const float* __restrict__ keysrc,
    const float* __restrict__ query, const float* __restrict__ Wv,
    const float* __restrict__ Wk, const float* __restrict__ Wq,
    const float* __restrict__ Wout,
    uint16_t* __restrict__ qp, uint16_t* __restrict__ kp,
    uint16_t* __restrict__ vp, uint16_t* __restrict__ wbf) {
  const int t = threadIdx.x, w = t >> 6, lane = t & 63;
  const int quad = lane >> 4, l16 = lane & 15;
  const int wid = blockIdx.x * 4 + w;
  const int mat = wid >> 10, sub = wid & 1023;

  if (mat == 3) {  // Wout f32 -> bf16
#pragma unroll
    for (int i = 0; i < 4; ++i) {
      int idx = sub * 256 + i * 64 + lane;
      float4 v = ((const float4*)Wout)[idx];
      uint2 p;
      p.x = pack2(v.x, v.y);
      p.y = pack2(v.z, v.w);
      ((uint2*)wbf)[idx] = p;
    }
    return;
  }

  floatx4 c[4][4];
#pragma unroll
  for (int i = 0; i < 4; ++i)
#pragma unroll
    for (int j = 0; j < 4; ++j) c[i][j] = floatx4{0.f, 0.f, 0.f, 0.f};

  if (mat < 2) {
    // Q/K: A = W rows (m=e), B = x rows (n=r) -> D[e][r]; lane holds 4 consecutive e.
    const float* src = mat ? keysrc : query;
    const float* W   = mat ? Wk : Wq;
    const float asc  = mat ? 1.f : QSCALE;
    uint16_t* dst    = mat ? kp : qp;
    const int R0 = sub * 64;
    short8 a[4][2], b[4][2];
#pragma unroll
    for (int dc = 0; dc < 2; ++dc) {
#pragma unroll
      for (int f = 0; f < 4; ++f) {
        a[f][dc] = ld8bf(W + (size_t)(f * 16 + l16) * 64 + dc * 32 + quad * 8, asc);
        b[f][dc] = ld8bf(src + (size_t)(R0 + f * 16 + l16) * 64 + dc * 32 + quad * 8, 1.f);
      }
    }
#pragma unroll
    for (int dc = 0; dc < 2; ++dc)
#pragma unroll
      for (int mf = 0; mf < 4; ++mf)
#pragma unroll
        for (int nf = 0; nf < 4; ++nf)
          c[mf][nf] = __builtin_amdgcn_mfma_f32_16x16x32_bf16(a[mf][dc], b[nf][dc], c[mf][nf], 0, 0, 0);
#pragma unroll
    for (int nf = 0; nf < 4; ++nf) {
      int r = R0 + nf * 16 + l16;
      int h = r & 15, l = (r >> 4) & 2047, n = r >> 15;
      uint16_t* drow = dst + ((size_t)(n * 16 + h) * 2048 + l) * 64;
#pragma unroll
      for (int mf = 0; mf < 4; ++mf) {
        uint2 pk;
        pk.x = pack2(c[mf][nf][0], c[mf][nf][1]);
        pk.y = pack2(c[mf][nf][2], c[mf][nf][3]);
        *(uint2*)(drow + mf * 16 + quad * 4) = pk;
      }
    }
  } else {
    // V^T: A = x rows (m=l), B = Wv rows (n=d) -> D[l][d]; vp[nh][d][l] in f16.
    const int nh = sub >> 5, L0 = (sub & 31) * 64;
    const int n = nh >> 4, h = nh & 15;
    short8 a[4][2], b[4][2];
#pragma unroll
    for (int dc = 0; dc < 2; ++dc) {
#pragma unroll
      for (int f = 0; f < 4; ++f) {
        a[f][dc] = ld8bf(values + (size_t)(n * 2048 + L0 + f * 16 + l16) * 1024 + h * 64 + dc * 32 + quad * 8, 1.f);
        b[f][dc] = ld8bf(Wv + (size_t)(f * 16 + l16) * 64 + dc * 32 + quad * 8, 1.f);
      }
    }
#pragma unroll
    for (int dc = 0; dc < 2; ++dc)
#pragma unroll
      for (int mf = 0; mf < 4; ++mf)
#pragma unroll
        for (int nf = 0; nf < 4; ++nf)
          c[mf][nf] = __builtin_amdgcn_mfma_f32_16x16x32_bf16(a[mf][dc], b[nf][dc], c[mf][nf], 0, 0, 0);
#pragma unroll
    for (int nf = 0; nf < 4; ++nf) {
      int d = nf * 16 + l16;
      uint16_t* drow = vp + ((size_t)nh * 64 + d) * 2048 + L0;
#pragma unroll
      for (int mf = 0; mf < 4; ++mf) {
        uint2 pk;
        pk.x = packh2(c[mf][nf][0], c[mf][nf][1]);
        pk.y = packh2(c[mf][nf][2], c[mf][nf][3]);
        *(uint2*)(drow + mf * 16 + quad * 4) = pk;
      }
    }
  }
}

// ---------------- Flash attention: 32x32 MFMA, 2-wave blocks, 4 blocks/CU -----------
// Per (64key x 32q) iter: 8 QK + 4 ones + 8 PV at 32x32x16 = 160 MFMA-cyc (vs 240 at
// 16x16) and 16 b128 LDS reads (vs 24 mixed) — same work, fewer issue slots. 32 q per
// wave keeps R0's 2x LDS amortization; 128-thread blocks give grid 32x32=1024 = 4
// blocks/CU for barrier hiding (R0's proven schedule: 2-buf + __syncthreads).
// S(32x32) C-layout: col=lane&31=q, row=key=(reg&3)+8*(reg>>2)+4*(lane>>5); the PV
// B-frag (k=hi*8+i) is built from it with 8 cvt_pkrtz + 4 permlane32_swap per kt.
// Swizzle: chunk ^= (row&7) ^ ((row>>3)&3), applied on BOTH stage source and reads.
__global__ __launch_bounds__(128, 2) void flash_kernel(const uint16_t* __restrict__ qp,
                                                       const uint16_t* __restrict__ kp,
                                                       const uint16_t* __restrict__ vp,
                                                       uint16_t* __restrict__ xg) {
  constexpr int kbn = 32;
  __shared__ uint16_t Kt[2][64 * 64];    // swizzled [key][d] bf16
  __shared__ uint16_t Vt[2][64 * 64];    // swizzled [d][key] f16
  const int t = threadIdx.x;
  const int w = t >> 6, lane = t & 63, hi = lane >> 5, l32 = lane & 31;
  const int nh = blockIdx.x, qt = blockIdx.y;
  const int q0w = qt * 64 + w * 32;      // 32 q-rows per wave
  const uint16_t* Qb = qp + (size_t)nh * Lseq * HD;
  const uint16_t* Kb = kp + (size_t)nh * Lseq * HD;
  const uint16_t* Vb = vp + (size_t)nh * HD * Lseq;
  const int srow = lane >> 3, sc8 = (lane & 7) ^ (lane >> 3);  // staging swizzle base

  // Q B-frags (32x32x16: lane holds B[k=hi*8+i][col=l32], k = d within dc-slice)
  short8 bq[4];
#pragma unroll
  for (int dc = 0; dc < 4; ++dc)
    bq[dc] = *(const short8*)(Qb + (size_t)(q0w + l32) * 64 + dc * 16 + hi * 8);

  floatx16 o[2], lfr;   // O^T frags (dt=0,1) + ones-MFMA l accumulator
#pragma unroll
  for (int r = 0; r < 16; ++r) { o[0][r] = 0.f; o[1][r] = 0.f; lfr[r] = 0.f; }
  const _Float16 one = (_Float16)1.0f;
  const half8 vones = {one, one, one, one, one, one, one, one};

  auto stage = [&](int tile, int buf) {  // 8 DMA instrs/wave = K+V 64-key tile
#pragma unroll
    for (int i = 0; i < 4; ++i) {
      int r0 = w * 32 + i * 8;
      int sc = sc8 ^ i;  // (row>>3)&3 == i for rows r0..r0+7
      gl_lds16(Kb + (size_t)tile * 4096 + (r0 + srow) * 64 + sc * 8, &Kt[buf][r0 * 64]);
      gl_lds16(Vb + (size_t)(r0 + srow) * Lseq + tile * 64 + sc * 8, &Vt[buf][r0 * 64]);
    }
  };

  stage(0, 0);

  for (int kb = 0; kb < kbn; ++kb) {
    __syncthreads();
    const int cur = kb & 1;
    if (kb + 1 < kbn) stage(kb + 1, cur ^ 1);

#pragma unroll
    for (int kt = 0; kt < 2; ++kt) {
      // S^T(32keys x 32q) = K_tile · Q^T, K=16 per step over d=64
      floatx16 s;
#pragma unroll
      for (int r = 0; r < 16; ++r) s[r] = 0.f;
      const int krow = kt * 32 + l32;
      const int ksw = (krow & 7) ^ ((krow >> 3) & 3);
#pragma unroll
      for (int dc = 0; dc < 4; ++dc) {
        short8 ak = *(const short8*)(&Kt[cur][krow * 64 + (((dc << 1) | hi) ^ ksw) * 8]);
        s = __builtin_amdgcn_mfma_f32_32x32x16_bf16(ak, bq[dc], s, 0, 0, 0);
      }
      // p = exp2(s); repack to two 16-key B-frags via cvt_pkrtz + permlane32_swap.
      // reg r holds key (r&3)+8*(r>>2)+4*hi: regs 0-7 -> keys 0..15, 8-15 -> 16..31.
      uint32_t a0 = packh2(__builtin_amdgcn_exp2f(s[0]), __builtin_amdgcn_exp2f(s[1]));
      uint32_t a1 = packh2(__builtin_amdgcn_exp2f(s[2]), __builtin_amdgcn_exp2f(s[3]));
      uint32_t b0 = packh2(__builtin_amdgcn_exp2f(s[4]), __builtin_amdgcn_exp2f(s[5]));
      uint32_t b1 = packh2(__builtin_amdgcn_exp2f(s[6]), __builtin_amdgcn_exp2f(s[7]));
      uint32_t c0 = packh2(__builtin_amdgcn_exp2f(s[8]), __builtin_amdgcn_exp2f(s[9]));
      uint32_t c1 = packh2(__builtin_amdgcn_exp2f(s[10]), __builtin_amdgcn_exp2f(s[11]));
      uint32_t d0 = packh2(__builtin_amdgcn_exp2f(s[12]), __builtin_amdgcn_exp2f(s[13]));
      uint32_t d1 = packh2(__builtin_amdgcn_exp2f(s[14]), __builtin_amdgcn_exp2f(s[15]));
      pl32(a0, b0); pl32(a1, b1); pl32(c0, d0); pl32(c1, d1);
      union { half8 h; uint32_t u[4]; } f0, f1;
      f0.u[0] = a0; f0.u[1] = a1; f0.u[2] = b0; f0.u[3] = b1;  // keys kt*32 + 0..15
      f1.u[0] = c0; f1.u[1] = c1; f1.u[2] = d0; f1.u[3] = d1;  // keys kt*32 + 16..31

      lfr = __builtin_amdgcn_mfma_f32_32x32x16_f16(vones, f0.h, lfr, 0, 0, 0);
      lfr = __builtin_amdgcn_mfma_f32_32x32x16_f16(vones, f1.h, lfr, 0, 0, 0);

      // O^T += V^T · P
#pragma unroll
      for (int dt = 0; dt < 2; ++dt) {
        const int vrow = dt * 32 + l32;
        const int vsw = (vrow & 7) ^ ((vrow >> 3) & 3);
        half8 av0 = *(const half8*)(&Vt[cur][vrow * 64 + ((kt * 4 + hi) ^ vsw) * 8]);
        o[dt] = __builtin_amdgcn_mfma_f32_32x32x16_f16(av0, f0.h, o[dt], 0, 0, 0);
        half8 av1 = *(const half8*)(&Vt[cur][vrow * 64 + ((kt * 4 + 2 + hi) ^ vsw) * 8]);
        o[dt] = __builtin_amdgcn_mfma_f32_32x32x16_f16(av1, f1.h, o[dt], 0, 0, 0);
      }
    }
  }

  // epilogue: X[n*2048+q][h*64+d] = O^T[d][q]/l_q as bf16. lfr col = l32 = own q,
  // so every lane reads its l from lfr[0] directly. d = dt*32 + rg*8 + 4*hi + {0..3}.
  const int nn = nh >> 4, h = nh & 15;
  const float inv = __builtin_amdgcn_rcpf(lfr[0]);
  uint16_t* xr = xg + ((size_t)(nn * 2048 + q0w + l32)) * 1024 + h * 64;
#pragma unroll
  for (int dt = 0; dt < 2; ++dt)
#pragma unroll
    for (int rg = 0; rg < 4; ++rg) {
      int dd = dt * 32 + rg * 8 + 4 * hi;
      uint2 pk;
      pk.x = pack2(o[dt][rg * 4] * inv, o[dt][rg * 4 + 1] * inv);
      pk.y = pack2(o[dt][rg * 4 + 2] * inv, o[dt][rg * 4 + 3] * inv);
      *(uint2*)(xr + dd) = pk;
    }
}

// ---------------- out GEMM: out = X @ Wout^T + bias, 64x128 tiles -------------------
// Counted-vmcnt 3-buffer schedule (6 DMAs/tile/wave -> vmcnt(6)).
// Grid (x=64 mblk, y=8 obk): linear%8 = mblk%8 -> all 8 obk sharers of an X slab on
// one XCD. LDS 72KB -> 2 blocks/CU, grid 512 = 2/CU resident.
__global__ __launch_bounds__(256, 2) void out_gemm(const uint16_t* __restrict__ Xg,
                                                   const uint16_t* __restrict__ Wb,
                                                   const float* __restrict__ bias,
                                                   float* __restrict__ out) {
  __shared__ uint16_t Xt[3][64 * 64];
  __shared__ uint16_t Wt[3][128 * 64];
  const int t = threadIdx.x, w = t >> 6, lane = t & 63, quad = lane >> 4, l16 = lane & 15;
  const int m0 = blockIdx.x * 64, o0 = blockIdx.y * 128;
  const int srow = lane >> 3, sc8 = (lane & 7) ^ (lane >> 3);

  floatx4 acc[8];
#pragma unroll
  for (int j = 0; j < 8; ++j) acc[j] = floatx4{0.f, 0.f, 0.f, 0.f};

  auto stage = [&](int buf, int kt) {  // 6 DMA instrs/wave
#pragma unroll
    for (int i = 0; i < 2; ++i) {   // X: 16 rows/wave
      int r0 = w * 16 + i * 8;
      gl_lds16(Xg + (size_t)(m0 + r0 + srow) * 1024 + kt * 64 + sc8 * 8, &Xt[buf][r0 * 64]);
    }
#pragma unroll
    for (int i = 0; i < 4; ++i) {   // W: 32 rows/wave
      int r0 = w * 32 + i * 8;
      gl_lds16(Wb + (size_t)(o0 + r0 + srow) * 1024 + kt * 64 + sc8 * 8, &Wt[buf][r0 * 64]);
    }
  };

  stage(0, 0);
  stage(1, 1);

  int cur = 0;
  for (int kt = 0; kt < 16; ++kt) {
    if (kt + 1 < 16) asm volatile("s_waitcnt vmcnt(6)" ::: "memory");
    else             asm volatile("s_waitcnt vmcnt(0)" ::: "memory");
    __builtin_amdgcn_s_barrier();
    if (kt + 2 < 16) {
      int tgt = cur + 2; if (tgt >= 3) tgt -= 3;
      stage(tgt, kt + 2);
    }
#pragma unroll
    for (int kc = 0; kc < 2; ++kc) {
      int ra = w * 16 + l16;
      short8 a = *(const short8*)(&Xt[cur][ra * 64 + ((kc * 4 + quad) ^ (ra & 7)) * 8]);
#pragma unroll
      for (int nf = 0; nf < 8; ++nf) {
        int rb = nf * 16 + l16;
        short8 b = *(const short8*)(&Wt[cur][rb * 64 + ((kc * 4 + quad) ^ (rb & 7)) * 8]);
        acc[nf] = __builtin_amdgcn_mfma_f32_16x16x32_bf16(a, b, acc[nf], 0, 0, 0);
      }
    }
    asm volatile("s_waitcnt lgkmcnt(0)" ::: "memory");
    cur = (cur + 1 == 3) ? 0 : cur + 1;
  }

#pragma unroll
  for (int nf = 0; nf < 8; ++nf) {
    float bv = bias[o0 + nf * 16 + l16];
#pragma unroll
    for (int r = 0; r < 4; ++r)
      out[(size_t)(m0 + w * 16 + quad * 4 + r) * 1024 + o0 + nf * 16 + l16] = acc[nf][r] + bv;
  }
}

extern "C" void kernel_launch(void* const* d_in, const int* in_sizes, int n_in,
                              void* d_out, int out_size, void* d_ws, size_t ws_size,
                              hipStream_t stream) {
  const float* values = (const float*)d_in[0];
  const float* keys   = (const float*)d_in[1];
  const float* query  = (const float*)d_in[2];
  const float* Wv     = (const float*)d_in[3];
  const float* Wk     = (const float*)d_in[4];
  const float* Wq     = (const float*)d_in[5];
  const float* Wout   = (const float*)d_in[6];
  const float* bout   = (const float*)d_in[7];
  float* out = (float*)d_out;
  (void)ws_size;

  uint16_t* ws  = (uint16_t*)d_ws;
  uint16_t* qp  = ws;                                // 8 MB bf16 [nh][l][d]
  uint16_t* kp  = ws + (size_t)4194304;              // 8 MB bf16 [nh][l][d]
  uint16_t* vp  = ws + (size_t)8388608;              // 8 MB f16  [nh][d][l]
  uint16_t* wbf = ws + (size_t)12582912;             // 2 MB bf16 Wout
  uint16_t* xp  = ws + (size_t)13631488;             // 8 MB bf16 X = normalized attn out

  prep_kernel<<<dim3(1024), dim3(256), 0, stream>>>(values, keys, query, Wv, Wk, Wq, Wout,
                                                    qp, kp, vp, wbf);
  flash_kernel<<<dim3(32, 32), dim3(128), 0, stream>>>(qp, kp, vp, xp);
  out_gemm<<<dim3(64, 8), dim3(256), 0, stream>>>(xp, wbf, bout, out);
}

// Round 7
// 181.067 us; speedup vs baseline: 1.0220x; 1.0220x over previous
//
#include <hip/hip_runtime.h>
#include <cstdint>

typedef __attribute__((ext_vector_type(8))) short short8;      // 8 bf16 = 4 VGPRs
typedef __attribute__((ext_vector_type(4))) float floatx4;     // MFMA C/D frag
typedef __attribute__((ext_vector_type(4))) _Float16 half4;    // 16x16x16 f16 A/B frag

#define DEV __device__ __forceinline__

constexpr int NB = 2, Lseq = 2048, NH = 16, HD = 64, EMB = 1024;
// fold softmax scale (1/sqrt(1024)) and log2(e) into Wq so flash uses exp2
constexpr float QSCALE = 0.03125f * 1.4426950408889634f;

// pack two f32 -> two bf16 in one dword (round-half-up via bias, then v_perm)
DEV uint32_t pack2(float lo, float hi) {
  uint32_t a = __builtin_bit_cast(uint32_t, lo) + 0x8000u;
  uint32_t b = __builtin_bit_cast(uint32_t, hi) + 0x8000u;
  return __builtin_amdgcn_perm(b, a, 0x07060302);
}

DEV uint32_t packh2(float lo, float hi) {  // two f32 -> packed f16 dword
  return __builtin_bit_cast(uint32_t, __builtin_amdgcn_cvt_pkrtz(lo, hi));
}

DEV void gl_lds16(const void* g, void* l) {  // async global->LDS, 16B/lane
  __builtin_amdgcn_global_load_lds((const __attribute__((address_space(1))) void*)g,
                                   (__attribute__((address_space(3))) void*)l, 16, 0, 0);
}

// load 8 consecutive f32, scale, convert to a bf16 MFMA frag chunk
DEV short8 ld8bf(const float* p, float sc) {
  float4 u = *(const float4*)p;
  float4 v = *(const float4*)(p + 4);
  union { short8 s; uint32_t d[4]; } r;
  r.d[0] = pack2(u.x * sc, u.y * sc);
  r.d[1] = pack2(u.z * sc, u.w * sc);
  r.d[2] = pack2(v.x * sc, v.y * sc);
  r.d[3] = pack2(v.z * sc, v.w * sc);
  return r.s;
}

// ---------------- prep: Q/K/V projections + Wout cvt, COALESCED stores --------------
// The old store path emitted 8B scattered global writes (consecutive lanes hit rows
// 4KB-256KB apart) -> heavy DRAM write amplification. Now each wave transposes its
// 64x64 output tile through 8KB wave-private LDS (16B-slot XOR swizzle; writes <=2-way,
// reads conflict-free) and stores 128B-contiguous chunks: 8 lanes cover one output row.
__global__ __launch_bounds__(256) void prep_kernel(
    const float* __restrict__ values, const float* __restrict__ keysrc,
    const float* __restrict__ query, const float* __restrict__ Wv,
    const float* __restrict__ Wk, const float* __restrict__ Wq,
    const float* __restrict__ Wout,
    uint16_t* __restrict__ qp, uint16_t* __restrict__ kp,
    uint16_t* __restrict__ vp, uint16_t* __restrict__ wbf) {
  __shared__ uint16_t Tp[4][64 * 64];   // 8KB per wave, wave-private
  const int t = threadIdx.x, w = t >> 6, lane = t & 63;
  const int quad = lane >> 4, l16 = lane & 15;
  const int wid = blockIdx.x * 4 + w;
  const int mat = wid >> 10, sub = wid & 1023;

  if (mat == 3) {  // Wout f32 -> bf16 (already coalesced)
#pragma unroll
    for (int i = 0; i < 4; ++i) {
      int idx = sub * 256 + i * 64 + lane;
      float4 v = ((const float4*)Wout)[idx];
      uint2 p;
      p.x = pack2(v.x, v.y);
      p.y = pack2(v.z, v.w);
      ((uint2*)wbf)[idx] = p;
    }
    return;
  }

  uint16_t* T = Tp[w];
  floatx4 c[4][4];
#pragma unroll
  for (int i = 0; i < 4; ++i)
#pragma unroll
    for (int j = 0; j < 4; ++j) c[i][j] = floatx4{0.f, 0.f, 0.f, 0.f};

  if (mat < 2) {
    // Q/K: A = W rows (m=e), B = x rows (n=r) -> D[e][r]; lane holds 4 consecutive e.
    const float* src = mat ? keysrc : query;
    const float* W   = mat ? Wk : Wq;
    const float asc  = mat ? 1.f : QSCALE;
    uint16_t* dst    = mat ? kp : qp;
    const int R0 = sub * 64;
    short8 a[4][2], b[4][2];
#pragma unroll
    for (int dc = 0; dc < 2; ++dc) {
#pragma unroll
      for (int f = 0; f < 4; ++f) {
        a[f][dc] = ld8bf(W + (size_t)(f * 16 + l16) * 64 + dc * 32 + quad * 8, asc);
        b[f][dc] = ld8bf(src + (size_t)(R0 + f * 16 + l16) * 64 + dc * 32 + quad * 8, 1.f);
      }
    }
#pragma unroll
    for (int dc = 0; dc < 2; ++dc)
#pragma unroll
      for (int mf = 0; mf < 4; ++mf)
#pragma unroll
        for (int nf = 0; nf < 4; ++nf)
          c[mf][nf] = __builtin_amdgcn_mfma_f32_16x16x32_bf16(a[mf][dc], b[nf][dc], c[mf][nf], 0, 0, 0);

    // LDS tile T[rl][e] (rl = local r, e contiguous): frag (mf,nf) -> 8B at fixed rl.
#pragma unroll
    for (int nf = 0; nf < 4; ++nf) {
      int rl = nf * 16 + l16;
      int swz = (rl & 7) ^ (((rl >> 3) & 1) << 2);
#pragma unroll
      for (int mf = 0; mf < 4; ++mf) {
        uint2 pk;
        pk.x = pack2(c[mf][nf][0], c[mf][nf][1]);
        pk.y = pack2(c[mf][nf][2], c[mf][nf][3]);
        int s16 = (mf * 2 + (quad >> 1)) ^ swz;
        *(uint2*)(&T[rl * 64 + s16 * 8 + (quad & 1) * 4]) = pk;
      }
    }
    // read back row-major, store 128B-contiguous (8 lanes per (h,l) output row)
#pragma unroll
    for (int p = 0; p < 8; ++p) {
      int rl2 = p * 8 + (lane >> 3), cch = lane & 7;
      int swz = (rl2 & 7) ^ (((rl2 >> 3) & 1) << 2);
      short8 vch = *(const short8*)(&T[rl2 * 64 + ((cch ^ swz) * 8)]);
      int r = R0 + rl2;
      int h = r & 15, l = (r >> 4) & 2047, n = r >> 15;
      *(short8*)(dst + ((size_t)(n * 16 + h) * 2048 + l) * 64 + cch * 8) = vch;
    }
  } else {
    // V^T: A = x rows (m=l), B = Wv rows (n=d) -> D[l][d]; vp[nh][d][l] in f16.
    const int nh = sub >> 5, L0 = (sub & 31) * 64;
    const int n = nh >> 4, h = nh & 15;
    short8 a[4][2], b[4][2];
#pragma unroll
    for (int dc = 0; dc < 2; ++dc) {
#pragma unroll
      for (int f = 0; f < 4; ++f) {
        a[f][dc] = ld8bf(values + (size_t)(n * 2048 + L0 + f * 16 + l16) * 1024 + h * 64 + dc * 32 + quad * 8, 1.f);
        b[f][dc] = ld8bf(Wv + (size_t)(f * 16 + l16) * 64 + dc * 32 + quad * 8, 1.f);
      }
    }
#pragma unroll
    for (int dc = 0; dc < 2; ++dc)
#pragma unroll
      for (int mf = 0; mf < 4; ++mf)
#pragma unroll
        for (int nf = 0; nf < 4; ++nf)
          c[mf][nf] = __builtin_amdgcn_mfma_f32_16x16x32_bf16(a[mf][dc], b[nf][dc], c[mf][nf], 0, 0, 0);

    // LDS tile T[d][l_loc] (transposed vs frag): frag (mf,nf) -> 8B f16 at fixed d.
#pragma unroll
    for (int nf = 0; nf < 4; ++nf) {
      int d = nf * 16 + l16;
      int swz = (d & 7) ^ (((d >> 3) & 1) << 2);
#pragma unroll
      for (int mf = 0; mf < 4; ++mf) {
        uint2 pk;
        pk.x = packh2(c[mf][nf][0], c[mf][nf][1]);
        pk.y = packh2(c[mf][nf][2], c[mf][nf][3]);
        int s16 = (mf * 2 + (quad >> 1)) ^ swz;
        *(uint2*)(&T[d * 64 + s16 * 8 + (quad & 1) * 4]) = pk;
      }
    }
#pragma unroll
    for (int p = 0; p < 8; ++p) {
      int d2 = p * 8 + (lane >> 3), cch = lane & 7;
      int swz = (d2 & 7) ^ (((d2 >> 3) & 1) << 2);
      short8 vch = *(const short8*)(&T[d2 * 64 + ((cch ^ swz) * 8)]);
      *(short8*)(vp + ((size_t)nh * 64 + d2) * 2048 + L0 + cch * 8) = vch;
    }
  }
}

// ---------------- Flash attention: q-split 16x16 (R5) + group-padded LDS ------------
// R5's proven structure (16 q/wave, full keys, 2-buf + __syncthreads, ones-MFMA l,
// 16 waves/CU). New: each 8-row LDS group padded to 1056B so row stride is not
// 0 mod 32 banks -> the 4-way conflict on PV's 8B half4 reads splits to <=2-way
// (free). K reads stay <=2-way. LDS 33KB -> still 4 blocks/CU.
__global__ __launch_bounds__(256, 4) void flash_kernel(const uint16_t* __restrict__ qp,
                                                       const uint16_t* __restrict__ kp,
                                                       const uint16_t* __restrict__ vp,
                                                       uint16_t* __restrict__ xg) {
  constexpr int kbn = 32;
  constexpr int GS = 528;                // u16 per 8-row group: 1024B data + 32B pad
  __shared__ uint16_t Kt[2][8 * GS];     // swizzled [key][d] bf16, grouped
  __shared__ uint16_t Vt[2][8 * GS];     // swizzled [d][key] f16, grouped
  const int t = threadIdx.x;
  const int w = t >> 6, lane = t & 63, quad = lane >> 4, l16 = lane & 15;
  const int nh = blockIdx.x, qt = blockIdx.y;
  const int q0 = qt * 64 + w * 16;       // 16 q-rows per wave
  const uint16_t* Qb = qp + (size_t)nh * Lseq * HD;
  const uint16_t* Kb = kp + (size_t)nh * Lseq * HD;
  const uint16_t* Vb = vp + (size_t)nh * HD * Lseq;
  const int srow = lane >> 3, sc8 = (lane & 7) ^ (lane >> 3);  // staging swizzle

  short8 bq[2];
  bq[0] = *(const short8*)(Qb + (q0 + l16) * 64 + quad * 8);
  bq[1] = *(const short8*)(Qb + (q0 + l16) * 64 + 32 + quad * 8);

  floatx4 o[4];      // O^T frags: row=d=db*16+quad*4+r, col=q=l16
  floatx4 lfr;       // ones^T P accumulator: every element = l_q for q=q0+l16
#pragma unroll
  for (int i = 0; i < 4; ++i) o[i] = floatx4{0.f, 0.f, 0.f, 0.f};
  lfr = floatx4{0.f, 0.f, 0.f, 0.f};
  const _Float16 one = (_Float16)1.0f;
  const half4 vone = {one, one, one, one};

#pragma unroll
  for (int i = 0; i < 2; ++i) {
    int r0 = w * 16 + i * 8;             // group index = w*2 + i
    gl_lds16(Kb + (r0 + srow) * 64 + sc8 * 8, &Kt[0][(w * 2 + i) * GS]);
    gl_lds16(Vb + (size_t)(r0 + srow) * Lseq + sc8 * 8, &Vt[0][(w * 2 + i) * GS]);
  }

  for (int kb = 0; kb < kbn; ++kb) {
    __syncthreads();
    const int cur = kb & 1;
    if (kb + 1 < kbn) {
      const int nxt = cur ^ 1;
      const uint16_t* kg = Kb + (kb + 1) * (64 * 64);
#pragma unroll
      for (int i = 0; i < 2; ++i) {
        int r0 = w * 16 + i * 8;
        gl_lds16(kg + (r0 + srow) * 64 + sc8 * 8, &Kt[nxt][(w * 2 + i) * GS]);
        gl_lds16(Vb + (size_t)(r0 + srow) * Lseq + (kb + 1) * 64 + sc8 * 8, &Vt[nxt][(w * 2 + i) * GS]);
      }
    }

    // S^T = K Q^T
    floatx4 s[4];
#pragma unroll
    for (int kb16 = 0; kb16 < 4; ++kb16) s[kb16] = floatx4{0.f, 0.f, 0.f, 0.f};
#pragma unroll
    for (int dc = 0; dc < 2; ++dc) {
#pragma unroll
      for (int kb16 = 0; kb16 < 4; ++kb16) {
        int row = kb16 * 16 + l16;
        const uint16_t* ka = &Kt[cur][(row >> 3) * GS + (row & 7) * 64 +
                                      (((dc * 4 + quad) ^ (row & 7)) * 8)];
        short8 ak = *(const short8*)ka;
        s[kb16] = __builtin_amdgcn_mfma_f32_16x16x32_bf16(ak, bq[dc], s[kb16], 0, 0, 0);
      }
    }

    // p = exp2(s), packed in-register as 16x16x16 B-frags; l via ones-MFMA
    half4 bp[4];
#pragma unroll
    for (int kb16 = 0; kb16 < 4; ++kb16) {
      float p0 = __builtin_amdgcn_exp2f(s[kb16][0]);
      float p1 = __builtin_amdgcn_exp2f(s[kb16][1]);
      float p2 = __builtin_amdgcn_exp2f(s[kb16][2]);
      float p3 = __builtin_amdgcn_exp2f(s[kb16][3]);
      union { half4 h4; uint32_t d[2]; } u;
      u.d[0] = packh2(p0, p1);
      u.d[1] = packh2(p2, p3);
      bp[kb16] = u.h4;
    }
#pragma unroll
    for (int kb16 = 0; kb16 < 4; ++kb16)
      lfr = __builtin_amdgcn_mfma_f32_16x16x16f16(vone, bp[kb16], lfr, 0, 0, 0);

    // O^T += V^T P
#pragma unroll
    for (int kb16 = 0; kb16 < 4; ++kb16) {
#pragma unroll
      for (int db = 0; db < 4; ++db) {
        int row = db * 16 + l16;
        int ch = (kb16 * 2 + (quad >> 1)) ^ (row & 7);
        const uint16_t* va = &Vt[cur][(row >> 3) * GS + (row & 7) * 64 +
                                      ch * 8 + (quad & 1) * 4];
        half4 av = *(const half4*)va;
        o[db] = __builtin_amdgcn_mfma_f32_16x16x16f16(av, bp[kb16], o[db], 0, 0, 0);
      }
    }
  }

  // epilogue: X[n*2048 + q][h*64 + d] = (O^T[d][q] / l_q) as bf16.
  const int nn = nh >> 4, h = nh & 15;
  const float inv = __builtin_amdgcn_rcpf(lfr[0]);
  uint16_t* xr = xg + ((size_t)(nn * 2048 + q0 + l16)) * 1024 + h * 64 + quad * 4;
#pragma unroll
  for (int db = 0; db < 4; ++db) {
    uint2 pk;
    pk.x = pack2(o[db][0] * inv, o[db][1] * inv);
    pk.y = pack2(o[db][2] * inv, o[db][3] * inv);
    *(uint2*)(xr + db * 16) = pk;
  }
}

// ---------------- out GEMM: out = X @ Wout^T + bias, 64x128 tiles -------------------
// Counted-vmcnt 3-buffer schedule (6 DMAs/tile/wave -> vmcnt(6)).
// Grid (x=64 mblk, y=8 obk): linear%8 = mblk%8 -> all 8 obk sharers of an X slab on
// one XCD. LDS 72KB -> 2 blocks/CU, grid 512 = 2/CU resident.
__global__ __launch_bounds__(256, 2) void out_gemm(const uint16_t* __restrict__ Xg,
                                                   const uint16_t* __restrict__ Wb,
                                                   const float* __restrict__ bias,
                                                   float* __restrict__ out) {
  __shared__ uint16_t Xt[3][64 * 64];
  __shared__ uint16_t Wt[3][128 * 64];
  const int t = threadIdx.x, w = t >> 6, lane = t & 63, quad = lane >> 4, l16 = lane & 15;
  const int m0 = blockIdx.x * 64, o0 = blockIdx.y * 128;
  const int srow = lane >> 3, sc8 = (lane & 7) ^ (lane >> 3);

  floatx4 acc[8];
#pragma unroll
  for (int j = 0; j < 8; ++j) acc[j] = floatx4{0.f, 0.f, 0.f, 0.f};

  auto stage = [&](int buf, int kt) {  // 6 DMA instrs/wave
#pragma unroll
    for (int i = 0; i < 2; ++i) {   // X: 16 rows/wave
      int r0 = w * 16 + i * 8;
      gl_lds16(Xg + (size_t)(m0 + r0 + srow) * 1024 + kt * 64 + sc8 * 8, &Xt[buf][r0 * 64]);
    }
#pragma unroll
    for (int i = 0; i < 4; ++i) {   // W: 32 rows/wave
      int r0 = w * 32 + i * 8;
      gl_lds16(Wb + (size_t)(o0 + r0 + srow) * 1024 + kt * 64 + sc8 * 8, &Wt[buf][r0 * 64]);
    }
  };

  stage(0, 0);
  stage(1, 1);

  int cur = 0;
  for (int kt = 0; kt < 16; ++kt) {
    if (kt + 1 < 16) asm volatile("s_waitcnt vmcnt(6)" ::: "memory");
    else             asm volatile("s_waitcnt vmcnt(0)" ::: "memory");
    __builtin_amdgcn_s_barrier();
    if (kt + 2 < 16) {
      int tgt = cur + 2; if (tgt >= 3) tgt -= 3;
      stage(tgt, kt + 2);
    }
#pragma unroll
    for (int kc = 0; kc < 2; ++kc) {
      int ra = w * 16 + l16;
      short8 a = *(const short8*)(&Xt[cur][ra * 64 + ((kc * 4 + quad) ^ (ra & 7)) * 8]);
#pragma unroll
      for (int nf = 0; nf < 8; ++nf) {
        int rb = nf * 16 + l16;
        short8 b = *(const short8*)(&Wt[cur][rb * 64 + ((kc * 4 + quad) ^ (rb & 7)) * 8]);
        acc[nf] = __builtin_amdgcn_mfma_f32_16x16x32_bf16(a, b, acc[nf], 0, 0, 0);
      }
    }
    asm volatile("s_waitcnt lgkmcnt(0)" ::: "memory");
    cur = (cur + 1 == 3) ? 0 : cur + 1;
  }

#pragma unroll
  for (int nf = 0; nf < 8; ++nf) {
    float bv = bias[o0 + nf * 16 + l16];
#pragma unroll
    for (int r = 0; r < 4; ++r)
      out[(size_t)(m0 + w * 16 + quad * 4 + r) * 1024 + o0 + nf * 16 + l16] = acc[nf][r] + bv;
  }
}

extern "C" void kernel_launch(void* const* d_in, const int* in_sizes, int n_in,
                              void* d_out, int out_size, void* d_ws, size_t ws_size,
                              hipStream_t stream) {
  const float* values = (const float*)d_in[0];
  const float* keys   = (const float*)d_in[1];
  const float* query  = (const float*)d_in[2];
  const float* Wv     = (const float*)d_in[3];
  const float* Wk     = (const float*)d_in[4];
  const float* Wq     = (const float*)d_in[5];
  const float* Wout   = (const float*)d_in[6];
  const float* bout   = (const float*)d_in[7];
  float* out = (float*)d_out;
  (void)ws_size;

  uint16_t* ws  = (uint16_t*)d_ws;
  uint16_t* qp  = ws;                                // 8 MB bf16 [nh][l][d]
  uint16_t* kp  = ws + (size_t)4194304;              // 8 MB bf16 [nh][l][d]
  uint16_t* vp  = ws + (size_t)8388608;              // 8 MB f16  [nh][d][l]
  uint16_t* wbf = ws + (size_t)12582912;             // 2 MB bf16 Wout
  uint16_t* xp  = ws + (size_t)13631488;             // 8 MB bf16 X = normalized attn out

  prep_kernel<<<dim3(1024), dim3(256), 0, stream>>>(values, keys, query, Wv, Wk, Wq, Wout,
                                                    qp, kp, vp, wbf);
  flash_kernel<<<dim3(32, 32), dim3(256), 0, stream>>>(qp, kp, vp, xp);
  out_gemm<<<dim3(64, 8), dim3(256), 0, stream>>>(xp, wbf, bout, out);
}